// Round 3
// baseline (399.714 us; speedup 1.0000x reference)
//
#include <hip/hip_runtime.h>
#include <hip/hip_bf16.h>
#include <hip/hip_cooperative_groups.h>

namespace cg = cooperative_groups;

typedef unsigned short u16;
typedef short bf16x8 __attribute__((ext_vector_type(8)));
typedef float f32x4 __attribute__((ext_vector_type(4)));
typedef int   i32x4 __attribute__((ext_vector_type(4)));

#define NB 8
#define NT 1024
#define ND 512
#define KSEL 307
#define PSTR 152   // attn P LDS row stride (elems)
#define TSTR 136   // gemm_wh transpose LDS row stride (elems)

__device__ __forceinline__ float bf2f(u16 u){
  union { unsigned int i; float f; } c; c.i = ((unsigned int)u) << 16; return c.f;
}
__device__ __forceinline__ u16 f2bf(float f){
  __hip_bfloat16 h = __float2bfloat16(f);
  u16 u; __builtin_memcpy(&u, &h, 2); return u;
}

// ---------- P1: MFMA bf16 GEMM Wh = bf16(x) @ W ; tile 128(t) x 64(f = one head)
__device__ __forceinline__ void phase_gemm_wh(char* smraw, int mb, int h, int tid,
    const float* __restrict__ x, const float* __restrict__ Wf,
    const float* __restrict__ a_src, const float* __restrict__ a_dst,
    u16* __restrict__ WhT, float* __restrict__ es, float* __restrict__ ed,
    float* __restrict__ mags, float* __restrict__ cn, float* __restrict__ rz){
  u16* smem = (u16*)smraw;
  u16* As = smem;                    // 128 x 40
  u16* Bs = smem + 5120;             // 64 x 40 (k-chunks xor-swizzled)
  int m0 = mb * 128;
  // fused zero-init: cn consumed by P3, rsum/rqsum by P4
  if (h == 0 && tid < 64) cn[mb * 64 + tid] = 0.f;
  if (h == 1) rz[mb * 256 + tid] = 0.f;
  int wv = tid >> 6, lane = tid & 63;
  int quad = lane >> 4, lr = lane & 15;
  f32x4 acc[2][4] = {};
  float sq[2] = {0.f, 0.f};
  int ar = (tid * 8) >> 5, ac = (tid * 8) & 31;
  const float* xa0 = &x[(size_t)(m0 + ar) * 512 + ac];
  const float* xa1 = xa0 + (size_t)64 * 512;
  int kk = (tid * 8) >> 6, f0 = (tid * 8) & 63;
  const float* wb = &Wf[((size_t)h << 15) + (size_t)kk * 64 + f0];
  int bbase = f0 * 40 + (((kk >> 3) ^ ((f0 >> 3) & 3)) * 8) + (kk & 7);
  f32x4 pa0 = *(const f32x4*)xa0, pa1 = *(const f32x4*)(xa0 + 4);
  f32x4 pa2 = *(const f32x4*)xa1, pa3 = *(const f32x4*)(xa1 + 4);
  f32x4 pb0 = *(const f32x4*)wb,  pb1 = *(const f32x4*)(wb + 4);
  for (int kt = 0; kt < 512; kt += 32){
    __syncthreads();
    {
      u16 pk[8];
      if (h == 0){
#pragma unroll
        for (int q = 0; q < 4; q++) sq[0] += pa0[q]*pa0[q] + pa1[q]*pa1[q];
#pragma unroll
        for (int q = 0; q < 4; q++) sq[1] += pa2[q]*pa2[q] + pa3[q]*pa3[q];
      }
#pragma unroll
      for (int q = 0; q < 4; q++){ pk[q] = f2bf(pa0[q]); pk[4+q] = f2bf(pa1[q]); }
      *(bf16x8*)&As[ar*40 + ac] = *(const bf16x8*)pk;
#pragma unroll
      for (int q = 0; q < 4; q++){ pk[q] = f2bf(pa2[q]); pk[4+q] = f2bf(pa3[q]); }
      *(bf16x8*)&As[(ar + 64)*40 + ac] = *(const bf16x8*)pk;
#pragma unroll
      for (int q = 0; q < 4; q++) Bs[bbase + q*40]       = f2bf(pb0[q]);
#pragma unroll
      for (int q = 0; q < 4; q++) Bs[bbase + (q+4)*40]   = f2bf(pb1[q]);
    }
    __syncthreads();
    if (kt < 480){
      pa0 = *(const f32x4*)(xa0 + kt + 32); pa1 = *(const f32x4*)(xa0 + kt + 36);
      pa2 = *(const f32x4*)(xa1 + kt + 32); pa3 = *(const f32x4*)(xa1 + kt + 36);
      pb0 = *(const f32x4*)(wb + (size_t)(kt + 32) * 64);
      pb1 = *(const f32x4*)(wb + (size_t)(kt + 32) * 64 + 4);
    }
    bf16x8 af[2], bfr[4];
#pragma unroll
    for (int i = 0; i < 2; i++) af[i] = *(const bf16x8*)&As[(wv*32 + i*16 + lr)*40 + quad*8];
#pragma unroll
    for (int i = 0; i < 4; i++){
      int f = i*16 + lr;
      bfr[i] = *(const bf16x8*)&Bs[f*40 + ((quad ^ ((f >> 3) & 3)) * 8)];
    }
#pragma unroll
    for (int mi = 0; mi < 2; mi++)
#pragma unroll
      for (int ni = 0; ni < 4; ni++)
        acc[mi][ni] = __builtin_amdgcn_mfma_f32_16x16x32_bf16(af[mi], bfr[ni], acc[mi][ni], 0, 0, 0);
  }
  // epilogue 0: row L2 norms (h==0 blocks only)
  if (h == 0){
#pragma unroll
    for (int i = 0; i < 2; i++){
      float s = sq[i];
      s += __shfl_xor(s, 1, 64);
      s += __shfl_xor(s, 2, 64);
      if ((tid & 3) == 0) mags[m0 + i*64 + (tid >> 2)] = sqrtf(s);
    }
  }
  // epilogue 1: edge dot products
  float asv[4], adv[4];
#pragma unroll
  for (int ni = 0; ni < 4; ni++){
    asv[ni] = a_src[h*64 + ni*16 + lr];
    adv[ni] = a_dst[h*64 + ni*16 + lr];
  }
#pragma unroll
  for (int mi = 0; mi < 2; mi++)
#pragma unroll
    for (int r = 0; r < 4; r++){
      float pes = 0.f, ped = 0.f;
#pragma unroll
      for (int ni = 0; ni < 4; ni++){
        pes += acc[mi][ni][r] * asv[ni];
        ped += acc[mi][ni][r] * adv[ni];
      }
#pragma unroll
      for (int mofs = 1; mofs < 16; mofs <<= 1){
        pes += __shfl_xor(pes, mofs, 64);
        ped += __shfl_xor(ped, mofs, 64);
      }
      if (lr == 0){
        int rowg = m0 + wv*32 + mi*16 + quad*4 + r;
        int bb_ = rowg >> 10, tt = rowg & 1023;
        es[(bb_ * 8 + h) * NT + tt] = pes;
        ed[(bb_ * 8 + h) * NT + tt] = ped;
      }
    }
  // epilogue 2: bf16 transpose via LDS -> WhT[(b*512 + h*64 + f)][t]
  __syncthreads();
  u16* Tr = smem;   // [f][t], stride TSTR
#pragma unroll
  for (int mi = 0; mi < 2; mi++)
#pragma unroll
    for (int ni = 0; ni < 4; ni++){
      int fl = ni*16 + lr;
      int tl = wv*32 + mi*16 + quad*4;
#pragma unroll
      for (int r = 0; r < 4; r++) Tr[fl*TSTR + tl + r] = f2bf(acc[mi][ni][r]);
    }
  __syncthreads();
  int f = tid >> 2, seg = tid & 3;
  int b_ = m0 >> 10;
  u16* dst = &WhT[(b_ * 512 + h * 64 + f) * NT + (m0 & 1023) + seg*32];
  const u16* srcp = &Tr[f*TSTR + seg*32];
#pragma unroll
  for (int k8 = 0; k8 < 4; k8++)
    *(bf16x8*)(dst + k8*8) = *(const bf16x8*)(srcp + k8*8);
}

// ---------- P2: exact top-k selection by ranking
__device__ __forceinline__ void phase_select(char* smraw, int b, int by, int tid,
    const float* __restrict__ mags, int* __restrict__ sel){
  float* sm = (float*)smraw;      // 4 KB
  for (int i = tid; i < NT; i += 256) sm[i] = mags[b * NT + i];
  __syncthreads();
  int tl = tid >> 2, tq = tid & 3;
  int t = by * 64 + tl;
  float m = sm[t];
  int cnt = 0;
  int s0 = tq * 256;
  for (int s = s0; s < s0 + 256; s++){
    float v = sm[s];
    cnt += (v > m) || (v == m && s < t);
  }
  cnt += __shfl_xor(cnt, 1, 64);
  cnt += __shfl_xor(cnt, 2, 64);
  if (tq == 0) sel[b * NT + t] = (cnt < KSEL) ? 1 : 0;
}

// ---------- P3: banded masked attention + elu + signed-sqrt -> t2b, cn atomics
__device__ __forceinline__ void phase_attn(char* smraw, int bh, int ty, int tid,
    const u16* __restrict__ WhT, const float* __restrict__ es, const float* __restrict__ ed,
    const int* __restrict__ sel, u16* __restrict__ t2b, float* __restrict__ cn){
  u16*   P    = (u16*)smraw;              // 64*PSTR*2 = 19456 B
  float* edw  = (float*)(smraw + 19456);  // 576 B
  int*   selw = (int*)  (smraw + 20032);  // 576 B
  float* esw  = (float*)(smraw + 20608);  // 256 B
  float* swv  = (float*)(smraw + 20864);  // 256 B (end 21120)
  int b = bh >> 3;
  int t0 = ty * 64;
  int wv = tid >> 6, lane = tid & 63;
  int quad = lane >> 4, lr = lane & 15;
  int s_base = t0 - 40;
  __syncthreads();   // protect LDS reuse from previous phase/pass
  for (int i = tid; i < 144; i += 256){
    int s = s_base + i;
    bool ok = (s >= 0 && s < NT);
    edw[i]  = ok ? ed[bh * NT + s] : 0.f;
    selw[i] = ok ? sel[b * NT + s] : 0;
  }
  if (tid < 64) esw[tid] = es[bh * NT + t0 + tid];
  {
    i32x4 z = {};
    for (int i = lane; i < 304; i += 64){
      int r16 = i / 19, c16 = i - r16 * 19;
      *(i32x4*)&P[(16*wv + r16) * PSTR + c16 * 8] = z;
    }
  }
  __syncthreads();
  {
    int tl = 16*wv + (lane >> 2);
    int q = lane & 3;
    float e_t = esw[tl];
    int sel_t = selw[tl + 40];
    float part = 0.f;
    for (int j = q; j <= 80; j += 4){
      int sw = tl + j;
      int s = s_base + sw;
      float w = 0.f;
      if (s >= 0 && s < NT && (sel_t | selw[sw])){
        float v = e_t + edw[sw];
        v = v > 0.f ? v : 0.2f * v;
        v = fminf(v, 60.f);
        w = bf2f(f2bf(__expf(v)));
      }
      part += w;
      if (w != 0.f) P[tl * PSTR + sw] = f2bf(w);
    }
    part += __shfl_xor(part, 1, 64);
    part += __shfl_xor(part, 2, 64);
    if (q == 0) swv[tl] = part;
  }
  __syncthreads();
  f32x4 acc[4] = {};
  const u16* vbase = WhT + (bh * 64) * NT;
#pragma unroll
  for (int ks = 0; ks < 96; ks += 32){
    bf16x8 afr = *(const bf16x8*)&P[(16*wv + lr) * PSTR + 16*wv + ks + quad*8];
    int tb = s_base + 16*wv + ks + quad*8;
    bool ok = (tb >= 0) && (tb < NT);
    bf16x8 zf = {};
#pragma unroll
    for (int jn = 0; jn < 4; jn++){
      bf16x8 bfr = ok ? *(const bf16x8*)&vbase[(16*jn + lr) * NT + tb] : zf;
      acc[jn] = __builtin_amdgcn_mfma_f32_16x16x32_bf16(afr, bfr, acc[jn], 0, 0, 0);
    }
  }
#pragma unroll
  for (int jn = 0; jn < 4; jn++){
    float ssum = 0.f;
#pragma unroll
    for (int r = 0; r < 4; r++){
      int t_loc = 16*wv + quad*4 + r;
      float sw_ = swv[t_loc];
      float hp = acc[jn][r] / (sw_ > 0.f ? sw_ : 1.f);
      hp = hp > 0.f ? hp : (__expf(hp) - 1.f);
      float o = hp >= 0.f ? sqrtf(hp) : -sqrtf(-hp);
      ssum += o * o;
      t2b[(b * NT + t0 + t_loc) * ND + (bh & 7) * 64 + 16*jn + lr] = f2bf(o);
    }
    ssum += __shfl_xor(ssum, 16, 64);
    ssum += __shfl_xor(ssum, 32, 64);
    if (quad == 0) atomicAdd(&cn[b * ND + (bh & 7) * 64 + 16*jn + lr], ssum);
  }
}

// ---------- P4: GEMM2 Y = (t2b*scl) @ W2 + x + b2 ; fused LN partials
__device__ __forceinline__ void phase_gemm2(char* smraw, int mb, int nb, int tid,
    const u16* __restrict__ A, const float* __restrict__ W2f,
    const float* __restrict__ xres, const float* __restrict__ b2,
    const float* __restrict__ cn, float* __restrict__ Y,
    float* __restrict__ rsum, float* __restrict__ rqsum){
  u16*   As  = (u16*)smraw;               // 10240 B
  u16*   Bs  = (u16*)(smraw + 10240);     // 5120 B
  float* scl = (float*)(smraw + 15360);   // 2048 B (end 17408)
  int m0 = mb * 128, n0 = nb * 64;
  int wv = tid >> 6, lane = tid & 63;
  int quad = lane >> 4, lr = lane & 15;
  int bb0 = (m0 >> 10) << 9;
  __syncthreads();   // protect LDS reuse from previous phase
  for (int i = tid; i < 512; i += 256){
    float nv = sqrtf(cn[bb0 + i]);
    scl[i] = 1.f / fmaxf(nv, 1e-12f);
  }
  f32x4 acc[2][4] = {};
  int ar = (tid * 8) >> 5, ac = (tid * 8) & 31;
  const u16* ap0 = &A[(size_t)(m0 + ar) * 512 + ac];
  const u16* ap1 = ap0 + (size_t)64 * 512;
  int kk = (tid * 8) >> 6, j0 = (tid * 8) & 63;
  const float* w2b = &W2f[(size_t)kk * 512 + n0 + j0];
  int bbase = j0 * 40 + (((kk >> 3) ^ ((j0 >> 3) & 3)) * 8) + (kk & 7);
  bf16x8 ra0 = *(const bf16x8*)ap0;
  bf16x8 ra1 = *(const bf16x8*)ap1;
  f32x4 pb0 = *(const f32x4*)w2b, pb1 = *(const f32x4*)(w2b + 4);
  for (int kt = 0; kt < 512; kt += 32){
    __syncthreads();
    {
      u16 pk0[8], pk1[8];
#pragma unroll
      for (int q = 0; q < 8; q++){
        float sv = scl[kt + ac + q];
        pk0[q] = f2bf(bf2f((u16)ra0[q]) * sv);
        pk1[q] = f2bf(bf2f((u16)ra1[q]) * sv);
      }
      *(bf16x8*)&As[ar*40 + ac]        = *(const bf16x8*)pk0;
      *(bf16x8*)&As[(ar + 64)*40 + ac] = *(const bf16x8*)pk1;
#pragma unroll
      for (int q = 0; q < 4; q++) Bs[bbase + q*40]     = f2bf(pb0[q]);
#pragma unroll
      for (int q = 0; q < 4; q++) Bs[bbase + (q+4)*40] = f2bf(pb1[q]);
    }
    __syncthreads();
    if (kt < 480){
      ra0 = *(const bf16x8*)(ap0 + kt + 32);
      ra1 = *(const bf16x8*)(ap1 + kt + 32);
      pb0 = *(const f32x4*)(w2b + (size_t)(kt + 32) * 512);
      pb1 = *(const f32x4*)(w2b + (size_t)(kt + 32) * 512 + 4);
    }
    bf16x8 af[2], bfr[4];
#pragma unroll
    for (int i = 0; i < 2; i++) af[i] = *(const bf16x8*)&As[(wv*32 + i*16 + lr)*40 + quad*8];
#pragma unroll
    for (int i = 0; i < 4; i++){
      int f = i*16 + lr;
      bfr[i] = *(const bf16x8*)&Bs[f*40 + ((quad ^ ((f >> 3) & 3)) * 8)];
    }
#pragma unroll
    for (int mi = 0; mi < 2; mi++)
#pragma unroll
      for (int ni = 0; ni < 4; ni++)
        acc[mi][ni] = __builtin_amdgcn_mfma_f32_16x16x32_bf16(af[mi], bfr[ni], acc[mi][ni], 0, 0, 0);
  }
  float b2v[4];
#pragma unroll
  for (int ni = 0; ni < 4; ni++) b2v[ni] = b2[n0 + ni*16 + lr];
#pragma unroll
  for (int mi = 0; mi < 2; mi++){
    int rgb = m0 + wv*32 + mi*16 + quad*4;
#pragma unroll
    for (int r = 0; r < 4; r++){
      int row = rgb + r;
      float rs = 0.f, rq = 0.f;
#pragma unroll
      for (int ni = 0; ni < 4; ni++){
        int cg = n0 + ni*16 + lr;
        int idx = row * 512 + cg;
        float yv = acc[mi][ni][r] + xres[idx] + b2v[ni];
        Y[idx] = yv;
        rs += yv; rq += yv * yv;
      }
#pragma unroll
      for (int m2 = 1; m2 < 16; m2 <<= 1){
        rs += __shfl_xor(rs, m2, 64);
        rq += __shfl_xor(rq, m2, 64);
      }
      if (lr == 0){
        atomicAdd(&rsum[row], rs);
        atomicAdd(&rqsum[row], rq);
      }
    }
  }
}

// ---------- P5: LN apply (stats precomputed) + transpose
__device__ __forceinline__ void phase_outln(char* smraw, int xb, int b, int zb, int tid,
    const float* __restrict__ Y, const float* __restrict__ rsum,
    const float* __restrict__ rqsum, const float* __restrict__ g,
    const float* __restrict__ bb, float* __restrict__ out){
  float* mus  = (float*)smraw;            // 256 B
  float* rss  = (float*)(smraw + 256);    // 256 B
  float* tile = (float*)(smraw + 512);    // 64*65*4 = 16640 B (end 17152)
  int t0 = xb * 64;
  int cbase = zb * 128;
  __syncthreads();   // protect LDS reuse from previous phase
  if (tid < 64){
    int row = b * NT + t0 + tid;
    float m = rsum[row] * (1.f/512.f);
    float var = rqsum[row] * (1.f/512.f) - m * m;
    mus[tid] = m;
    rss[tid] = 1.f / sqrtf(var + 1e-5f);
  }
  __syncthreads();
  int j = tid & 63, i0 = tid >> 6;
  for (int c0 = cbase; c0 < cbase + 128; c0 += 64){
#pragma unroll
    for (int k = 0; k < 16; k++){
      int i = i0 + k * 4;
      float v = (Y[(b * NT + t0 + i) * ND + c0 + j] - mus[i]) * rss[i] * g[c0 + j] + bb[c0 + j];
      tile[i * 65 + j] = v;
    }
    __syncthreads();
#pragma unroll
    for (int k = 0; k < 16; k++){
      int jj = i0 + k * 4;   // d-local
      out[(b * ND + c0 + jj) * NT + t0 + j] = tile[j * 65 + jj];
    }
    __syncthreads();
  }
}

// ---------- mega kernel: whole pipeline, grid-wide sync between phases
__global__ void __launch_bounds__(256, 2)
k_mega(const float* __restrict__ x, const float* __restrict__ Wf,
       const float* __restrict__ a_src, const float* __restrict__ a_dst,
       const float* __restrict__ W2f, const float* __restrict__ b2,
       const float* __restrict__ ln_g, const float* __restrict__ ln_b,
       u16* __restrict__ WhT, float* __restrict__ es, float* __restrict__ ed,
       float* __restrict__ mags, int* __restrict__ sel, float* __restrict__ cn,
       float* __restrict__ rsum, float* __restrict__ rqsum, u16* __restrict__ t2b,
       float* __restrict__ Y, float* __restrict__ out){
  __shared__ __align__(16) char smraw[21184];
  cg::grid_group grid = cg::this_grid();
  int bid = blockIdx.x, tid = threadIdx.x;
  // P1: gemm_wh — 512 units, 1:1
  phase_gemm_wh(smraw, bid & 63, bid >> 6, tid, x, Wf, a_src, a_dst, WhT, es, ed, mags, cn, rsum);
  grid.sync();
  // P2: select — 128 units on first 128 blocks
  if (bid < 128) phase_select(smraw, bid >> 4, bid & 15, tid, mags, sel);
  grid.sync();
  // P3: attn — 1024 units, 2 per block (same bh, ty and ty+8)
  phase_attn(smraw, bid & 63, bid >> 6,       tid, WhT, es, ed, sel, t2b, cn);
  phase_attn(smraw, bid & 63, 8 + (bid >> 6), tid, WhT, es, ed, sel, t2b, cn);
  grid.sync();
  // P4: gemm2 — 512 units, 1:1
  phase_gemm2(smraw, bid & 63, bid >> 6, tid, t2b, W2f, x, b2, cn, Y, rsum, rqsum);
  grid.sync();
  // P5: outln — 512 units, 1:1
  phase_outln(smraw, bid & 15, (bid >> 4) & 7, bid >> 7, tid, Y, rsum, rqsum, ln_g, ln_b, out);
}

extern "C" void kernel_launch(void* const* d_in, const int* in_sizes, int n_in,
                              void* d_out, int out_size, void* d_ws, size_t ws_size,
                              hipStream_t stream) {
  (void)in_sizes; (void)n_in; (void)out_size; (void)ws_size;
  const float* x     = (const float*)d_in[0];
  const float* W     = (const float*)d_in[1];
  const float* a_src = (const float*)d_in[2];
  const float* a_dst = (const float*)d_in[3];
  const float* W2    = (const float*)d_in[4];
  const float* b2    = (const float*)d_in[5];
  const float* ln_g  = (const float*)d_in[6];
  const float* ln_b  = (const float*)d_in[7];
  char* ws = (char*)d_ws;
  int*   sel   = (int*)  (ws + 256);
  float* mags  = (float*)(ws + 33024);
  float* es    = (float*)(ws + 1124608);
  float* ed    = (float*)(ws + 1386752);
  float* cn    = (float*)(ws + 1648896);   // zeroed in P1 h==0 blocks
  float* rsum  = (float*)(ws + 1665280);   // zeroed in P1 h==1 blocks
  float* rqsum = (float*)(ws + 1698048);   // contiguous with rsum
  u16*   WhT   = (u16*)  (ws + 2097152);   // 8 MB; dead after P3
  u16*   t2b   = (u16*)  (ws + 18874368);  // 8 MB
  float* Y     = (float*)(ws + 2097152);   // 16 MB; overlays WhT after dead
  float* out   = (float*)d_out;

  void* args[] = {
    (void*)&x, (void*)&W, (void*)&a_src, (void*)&a_dst, (void*)&W2, (void*)&b2,
    (void*)&ln_g, (void*)&ln_b, (void*)&WhT, (void*)&es, (void*)&ed, (void*)&mags,
    (void*)&sel, (void*)&cn, (void*)&rsum, (void*)&rqsum, (void*)&t2b, (void*)&Y,
    (void*)&out
  };
  hipLaunchCooperativeKernel((const void*)k_mega, dim3(512), dim3(256), args, 0, stream);
}

// Round 4
// 143.687 us; speedup vs baseline: 2.7818x; 2.7818x over previous
//
#include <hip/hip_runtime.h>
#include <hip/hip_bf16.h>

typedef unsigned short u16;
typedef short bf16x8 __attribute__((ext_vector_type(8)));
typedef float f32x4 __attribute__((ext_vector_type(4)));
typedef int   i32x4 __attribute__((ext_vector_type(4)));

#define NB 8
#define NT 1024
#define ND 512
#define KSEL 307
#define PSTR 152   // attn P LDS row stride (elems)
#define TSTR 136   // gemm_wh transpose LDS row stride (elems)

__device__ __forceinline__ float bf2f(u16 u){
  union { unsigned int i; float f; } c; c.i = ((unsigned int)u) << 16; return c.f;
}
__device__ __forceinline__ u16 f2bf(float f){
  __hip_bfloat16 h = __float2bfloat16(f);
  u16 u; __builtin_memcpy(&u, &h, 2); return u;
}

// ---------- exact top-k selection by ranking; 4 threads per t, 64 t per block
__global__ void k_select(const float* __restrict__ mags, int* __restrict__ sel){
  __shared__ float sm[NT];
  int b = blockIdx.x;
  int tid = threadIdx.x;
  for (int i = tid; i < NT; i += 256) sm[i] = mags[b * NT + i];
  __syncthreads();
  int tl = tid >> 2, tq = tid & 3;
  int t = blockIdx.y * 64 + tl;
  float m = sm[t];
  int cnt = 0;
  int s0 = tq * 256;
  for (int s = s0; s < s0 + 256; s++){
    float v = sm[s];
    cnt += (v > m) || (v == m && s < t);
  }
  cnt += __shfl_xor(cnt, 1, 64);
  cnt += __shfl_xor(cnt, 2, 64);
  if (tq == 0) sel[b * NT + t] = (cnt < KSEL) ? 1 : 0;
}

// ---------- MFMA bf16 GEMM: Wh = bf16(x) @ W ; tile 128(t) x 64(f = one head)
//   Fused: cn zero (h==0), W2->bf16 W2T[n][k] transpose (h==2 pre-phase),
//          mags epilogue (h==0), es/ed edge dots, transposed bf16 WhT write.
__launch_bounds__(256, 3)
__global__ void k_gemm_wh(const float* __restrict__ x, const float* __restrict__ Wf,
                          const float* __restrict__ W2f,
                          const float* __restrict__ a_src, const float* __restrict__ a_dst,
                          u16* __restrict__ WhT, float* __restrict__ es, float* __restrict__ ed,
                          float* __restrict__ mags, float* __restrict__ cn,
                          u16* __restrict__ W2T){
  __shared__ u16 smem[8704];         // 17408 B; As(5120)+Bs(2560) alias Tr(64*TSTR) / f32 tile
  u16* As = smem;                    // 128 x 40
  u16* Bs = smem + 5120;             // 64 x 40 (k-chunks xor-swizzled)
  int m0 = blockIdx.x * 128;         // t-block
  int h  = blockIdx.y;               // head (n0 = h*64)
  int tid = threadIdx.x;
  // fused zero-init: cn consumed by k_attn
  if (h == 0 && tid < 64) cn[blockIdx.x * 64 + tid] = 0.f;
  // fused W2 transpose-convert: 64 tiles of 64x64, one per h==2 block
  if (h == 2){
    float* tile = (float*)smem;      // 64*65*4 = 16640 B <= 17408
    int kt0 = (blockIdx.x >> 3) * 64, n00 = (blockIdx.x & 7) * 64;
    int r = tid >> 6, cl = tid & 63;
#pragma unroll
    for (int p = 0; p < 16; p++)
      tile[(r + p*4)*65 + cl] = W2f[(size_t)(kt0 + r + p*4) * 512 + n00 + cl];
    __syncthreads();
#pragma unroll
    for (int p = 0; p < 16; p++){
      int orow = r + p*4;            // n-local
      W2T[(size_t)(n00 + orow) * 512 + kt0 + cl] = f2bf(tile[cl*65 + orow]);
    }
    __syncthreads();
  }
  int wv = tid >> 6, lane = tid & 63;
  int quad = lane >> 4, lr = lane & 15;
  f32x4 acc[2][4] = {};
  float sq[2] = {0.f, 0.f};
  int ar = (tid * 8) >> 5, ac = (tid * 8) & 31;
  const float* xa0 = &x[(size_t)(m0 + ar) * 512 + ac];
  const float* xa1 = xa0 + (size_t)64 * 512;
  int kk = (tid * 8) >> 6, f0 = (tid * 8) & 63;
  const float* wb = &Wf[((size_t)h << 15) + (size_t)kk * 64 + f0];
  int bbase = f0 * 40 + (((kk >> 3) ^ ((f0 >> 3) & 3)) * 8) + (kk & 7);
  f32x4 pa0 = *(const f32x4*)xa0, pa1 = *(const f32x4*)(xa0 + 4);
  f32x4 pa2 = *(const f32x4*)xa1, pa3 = *(const f32x4*)(xa1 + 4);
  f32x4 pb0 = *(const f32x4*)wb,  pb1 = *(const f32x4*)(wb + 4);
  for (int kt = 0; kt < 512; kt += 32){
    __syncthreads();
    {
      u16 pk[8];
      if (h == 0){
#pragma unroll
        for (int q = 0; q < 4; q++) sq[0] += pa0[q]*pa0[q] + pa1[q]*pa1[q];
#pragma unroll
        for (int q = 0; q < 4; q++) sq[1] += pa2[q]*pa2[q] + pa3[q]*pa3[q];
      }
#pragma unroll
      for (int q = 0; q < 4; q++){ pk[q] = f2bf(pa0[q]); pk[4+q] = f2bf(pa1[q]); }
      *(bf16x8*)&As[ar*40 + ac] = *(const bf16x8*)pk;
#pragma unroll
      for (int q = 0; q < 4; q++){ pk[q] = f2bf(pa2[q]); pk[4+q] = f2bf(pa3[q]); }
      *(bf16x8*)&As[(ar + 64)*40 + ac] = *(const bf16x8*)pk;
#pragma unroll
      for (int q = 0; q < 4; q++) Bs[bbase + q*40]       = f2bf(pb0[q]);
#pragma unroll
      for (int q = 0; q < 4; q++) Bs[bbase + (q+4)*40]   = f2bf(pb1[q]);
    }
    __syncthreads();
    if (kt < 480){
      pa0 = *(const f32x4*)(xa0 + kt + 32); pa1 = *(const f32x4*)(xa0 + kt + 36);
      pa2 = *(const f32x4*)(xa1 + kt + 32); pa3 = *(const f32x4*)(xa1 + kt + 36);
      pb0 = *(const f32x4*)(wb + (size_t)(kt + 32) * 64);
      pb1 = *(const f32x4*)(wb + (size_t)(kt + 32) * 64 + 4);
    }
    bf16x8 af[2], bfr[4];
#pragma unroll
    for (int i = 0; i < 2; i++) af[i] = *(const bf16x8*)&As[(wv*32 + i*16 + lr)*40 + quad*8];
#pragma unroll
    for (int i = 0; i < 4; i++){
      int f = i*16 + lr;
      bfr[i] = *(const bf16x8*)&Bs[f*40 + ((quad ^ ((f >> 3) & 3)) * 8)];
    }
#pragma unroll
    for (int mi = 0; mi < 2; mi++)
#pragma unroll
      for (int ni = 0; ni < 4; ni++)
        acc[mi][ni] = __builtin_amdgcn_mfma_f32_16x16x32_bf16(af[mi], bfr[ni], acc[mi][ni], 0, 0, 0);
  }
  // ---- epilogue 0: row L2 norms (4 lanes per row), h==0 blocks only
  if (h == 0){
#pragma unroll
    for (int i = 0; i < 2; i++){
      float s = sq[i];
      s += __shfl_xor(s, 1, 64);
      s += __shfl_xor(s, 2, 64);
      if ((tid & 3) == 0) mags[m0 + i*64 + (tid >> 2)] = sqrtf(s);
    }
  }
  // ---- epilogue 1: edge dot products
  float asv[4], adv[4];
#pragma unroll
  for (int ni = 0; ni < 4; ni++){
    asv[ni] = a_src[h*64 + ni*16 + lr];
    adv[ni] = a_dst[h*64 + ni*16 + lr];
  }
#pragma unroll
  for (int mi = 0; mi < 2; mi++)
#pragma unroll
    for (int r = 0; r < 4; r++){
      float pes = 0.f, ped = 0.f;
#pragma unroll
      for (int ni = 0; ni < 4; ni++){
        pes += acc[mi][ni][r] * asv[ni];
        ped += acc[mi][ni][r] * adv[ni];
      }
#pragma unroll
      for (int mofs = 1; mofs < 16; mofs <<= 1){
        pes += __shfl_xor(pes, mofs, 64);
        ped += __shfl_xor(ped, mofs, 64);
      }
      if (lr == 0){
        int rowg = m0 + wv*32 + mi*16 + quad*4 + r;
        int bb_ = rowg >> 10, tt = rowg & 1023;
        es[(bb_ * 8 + h) * NT + tt] = pes;
        ed[(bb_ * 8 + h) * NT + tt] = ped;
      }
    }
  // ---- epilogue 2: bf16 transpose via LDS -> WhT[(b*512 + h*64 + f)][t]
  __syncthreads();
  u16* Tr = smem;   // [f][t], stride TSTR
#pragma unroll
  for (int mi = 0; mi < 2; mi++)
#pragma unroll
    for (int ni = 0; ni < 4; ni++){
      int fl = ni*16 + lr;
      int tl = wv*32 + mi*16 + quad*4;
#pragma unroll
      for (int r = 0; r < 4; r++) Tr[fl*TSTR + tl + r] = f2bf(acc[mi][ni][r]);
    }
  __syncthreads();
  int f = tid >> 2, seg = tid & 3;
  int b_ = m0 >> 10;
  u16* dst = &WhT[(b_ * 512 + h * 64 + f) * NT + (m0 & 1023) + seg*32];
  const u16* srcp = &Tr[f*TSTR + seg*32];
#pragma unroll
  for (int k8 = 0; k8 < 4; k8++)
    *(bf16x8*)(dst + k8*8) = *(const bf16x8*)(srcp + k8*8);
}

// ---------- banded masked attention via MFMA + elu + signed-sqrt -> t2b (bf16)
//            + fused column sum-of-squares (atomicAdd into cn)
__launch_bounds__(256)
__global__ void k_attn(const u16* __restrict__ WhT, const float* __restrict__ es,
                       const float* __restrict__ ed, const int* __restrict__ sel,
                       u16* __restrict__ t2b, float* __restrict__ cn){
  __shared__ u16 P[64 * PSTR];
  __shared__ float edw[144];
  __shared__ int   selw[144];
  __shared__ float esw[64];
  __shared__ float swv[64];
  int bh = blockIdx.x;               // b*8+h
  int b = bh >> 3;
  int t0 = blockIdx.y * 64;
  int tid = threadIdx.x;
  int wv = tid >> 6, lane = tid & 63;
  int quad = lane >> 4, lr = lane & 15;
  int s_base = t0 - 40;
  for (int i = tid; i < 144; i += 256){
    int s = s_base + i;
    bool ok = (s >= 0 && s < NT);
    edw[i]  = ok ? ed[bh * NT + s] : 0.f;
    selw[i] = ok ? sel[b * NT + s] : 0;
  }
  if (tid < 64) esw[tid] = es[bh * NT + t0 + tid];
  {
    i32x4 z = {};
    for (int i = lane; i < 304; i += 64){
      int r16 = i / 19, c16 = i - r16 * 19;
      *(i32x4*)&P[(16*wv + r16) * PSTR + c16 * 8] = z;
    }
  }
  __syncthreads();
  {
    int tl = 16*wv + (lane >> 2);
    int q = lane & 3;
    float e_t = esw[tl];
    int sel_t = selw[tl + 40];
    float part = 0.f;
    for (int j = q; j <= 80; j += 4){
      int sw = tl + j;
      int s = s_base + sw;
      float w = 0.f;
      if (s >= 0 && s < NT && (sel_t | selw[sw])){
        float v = e_t + edw[sw];
        v = v > 0.f ? v : 0.2f * v;
        v = fminf(v, 60.f);
        w = bf2f(f2bf(__expf(v)));
      }
      part += w;
      if (w != 0.f) P[tl * PSTR + sw] = f2bf(w);
    }
    part += __shfl_xor(part, 1, 64);
    part += __shfl_xor(part, 2, 64);
    if (q == 0) swv[tl] = part;
  }
  __syncthreads();
  f32x4 acc[4] = {};
  const u16* vbase = WhT + (bh * 64) * NT;
#pragma unroll
  for (int ks = 0; ks < 96; ks += 32){
    bf16x8 afr = *(const bf16x8*)&P[(16*wv + lr) * PSTR + 16*wv + ks + quad*8];
    int tb = s_base + 16*wv + ks + quad*8;
    bool ok = (tb >= 0) && (tb < NT);
    bf16x8 zf = {};
#pragma unroll
    for (int jn = 0; jn < 4; jn++){
      bf16x8 bfr = ok ? *(const bf16x8*)&vbase[(16*jn + lr) * NT + tb] : zf;
      acc[jn] = __builtin_amdgcn_mfma_f32_16x16x32_bf16(afr, bfr, acc[jn], 0, 0, 0);
    }
  }
#pragma unroll
  for (int jn = 0; jn < 4; jn++){
    float ssum = 0.f;
#pragma unroll
    for (int r = 0; r < 4; r++){
      int t_loc = 16*wv + quad*4 + r;
      float sw_ = swv[t_loc];
      float hp = acc[jn][r] / (sw_ > 0.f ? sw_ : 1.f);
      hp = hp > 0.f ? hp : (__expf(hp) - 1.f);
      float o = hp >= 0.f ? sqrtf(hp) : -sqrtf(-hp);
      ssum += o * o;
      t2b[(b * NT + t0 + t_loc) * ND + (bh & 7) * 64 + 16*jn + lr] = f2bf(o);
    }
    ssum += __shfl_xor(ssum, 16, 64);
    ssum += __shfl_xor(ssum, 32, 64);
    if (quad == 0) atomicAdd(&cn[b * ND + (bh & 7) * 64 + 16*jn + lr], ssum);
  }
}

// ---------- GEMM2+LN fused: full-row tile 32(t) x 512(d), 512 threads, 256 blocks.
//   Y = (t2b*scl) @ W2 + x + b2 computed in regs; LN stats block-local;
//   normalized output written transposed ([B,D,T]) via LDS tile. No Y/rsum/rqsum.
__launch_bounds__(512)
__global__ void k_gemm2ln(const u16* __restrict__ A, const u16* __restrict__ W2T,
                          const float* __restrict__ xres, const float* __restrict__ b2,
                          const float* __restrict__ cn, const float* __restrict__ g,
                          const float* __restrict__ bb, float* __restrict__ out){
  __shared__ __align__(16) char smraw[69888];
  u16*   As  = (u16*)smraw;               // 32 x 40 = 2560 B
  u16*   Bs  = (u16*)(smraw + 2560);      // 512 x 40 = 40960 B (end 43520)
  float* scl = (float*)(smraw + 43520);   // 2048 B (end 45568)
  // post-K-loop aliases:
  float* T     = (float*)smraw;           // [512 d][33] f32 = 67584 B
  float* wpart = (float*)(smraw + 67584); // [2][8][32] = 2048 B
  float* mus   = (float*)(smraw + 69632); // 128 B
  float* rss   = (float*)(smraw + 69760); // 128 B
  int tid = threadIdx.x;
  int m0 = blockIdx.x * 32;               // global row base
  int b  = m0 >> 10, t0 = m0 & 1023;
  int w = tid >> 6, lane = tid & 63;
  int quad = lane >> 4, lr = lane & 15;
  // scl
  {
    float nv = sqrtf(cn[(b << 9) + tid]);
    scl[tid] = 1.f / fmaxf(nv, 1e-12f);
  }
  // staging prefetch (kt = 0)
  int ar = tid >> 2, ac = (tid & 3) * 8;        // A: threads 0..127
  const u16* ap = &A[(size_t)(m0 + ar) * 512 + ac];
  int nb_ = tid >> 2, c = (tid & 3) * 8;        // B: all threads, 4 reps
  bf16x8 ra = {}, rb[4];
  if (tid < 128) ra = *(const bf16x8*)ap;
#pragma unroll
  for (int rep = 0; rep < 4; rep++)
    rb[rep] = *(const bf16x8*)&W2T[(size_t)(nb_ + rep*128) * 512 + c];
  f32x4 acc[2][4] = {};
  for (int kt = 0; kt < 512; kt += 32){
    __syncthreads();
    if (tid < 128){
      u16 pk[8];
#pragma unroll
      for (int q = 0; q < 8; q++)
        pk[q] = f2bf(bf2f((u16)ra[q]) * scl[kt + ac + q]);
      *(bf16x8*)&As[ar*40 + ac] = *(const bf16x8*)pk;
    }
#pragma unroll
    for (int rep = 0; rep < 4; rep++)
      *(bf16x8*)&Bs[(nb_ + rep*128)*40 + c] = rb[rep];
    __syncthreads();
    if (kt < 480){
      if (tid < 128) ra = *(const bf16x8*)(ap + kt + 32);
#pragma unroll
      for (int rep = 0; rep < 4; rep++)
        rb[rep] = *(const bf16x8*)&W2T[(size_t)(nb_ + rep*128) * 512 + kt + 32 + c];
    }
    bf16x8 af[2], bfr[4];
#pragma unroll
    for (int mi = 0; mi < 2; mi++) af[mi] = *(const bf16x8*)&As[(mi*16 + lr)*40 + quad*8];
#pragma unroll
    for (int i = 0; i < 4; i++)
      bfr[i] = *(const bf16x8*)&Bs[(w*64 + i*16 + lr)*40 + quad*8];
#pragma unroll
    for (int mi = 0; mi < 2; mi++)
#pragma unroll
      for (int ni = 0; ni < 4; ni++)
        acc[mi][ni] = __builtin_amdgcn_mfma_f32_16x16x32_bf16(af[mi], bfr[ni], acc[mi][ni], 0, 0, 0);
  }
  // ---- epilogue: yv = acc + xres + b2 ; block-local LN stats
  float b2v[4];
#pragma unroll
  for (int ni = 0; ni < 4; ni++) b2v[ni] = b2[w*64 + ni*16 + lr];
  float yv[2][4][4];
#pragma unroll
  for (int mi = 0; mi < 2; mi++)
#pragma unroll
    for (int r = 0; r < 4; r++){
      int rl = mi*16 + quad*4 + r;
      float rs = 0.f, rq = 0.f;
#pragma unroll
      for (int ni = 0; ni < 4; ni++){
        int col = w*64 + ni*16 + lr;
        float v = acc[mi][ni][r] + xres[(size_t)(m0 + rl) * 512 + col] + b2v[ni];
        yv[mi][ni][r] = v;
        rs += v; rq += v * v;
      }
#pragma unroll
      for (int m2 = 1; m2 < 16; m2 <<= 1){
        rs += __shfl_xor(rs, m2, 64);
        rq += __shfl_xor(rq, m2, 64);
      }
      if (lr == 0){
        wpart[w*32 + rl]       = rs;
        wpart[256 + w*32 + rl] = rq;
      }
    }
  __syncthreads();     // wpart ready; all staging-LDS reads done
  if (tid < 32){
    float s = 0.f, q = 0.f;
#pragma unroll
    for (int wv2 = 0; wv2 < 8; wv2++){
      s += wpart[wv2*32 + tid];
      q += wpart[256 + wv2*32 + tid];
    }
    float mu = s * (1.f/512.f);
    float var = q * (1.f/512.f) - mu * mu;
    mus[tid] = mu;
    rss[tid] = 1.f / sqrtf(var + 1e-5f);
  }
  __syncthreads();
  // normalize into transpose tile T[d][t]
  float gv[4], bv[4];
#pragma unroll
  for (int ni = 0; ni < 4; ni++){
    gv[ni] = g[w*64 + ni*16 + lr];
    bv[ni] = bb[w*64 + ni*16 + lr];
  }
#pragma unroll
  for (int mi = 0; mi < 2; mi++)
#pragma unroll
    for (int r = 0; r < 4; r++){
      int rl = mi*16 + quad*4 + r;
      float mu = mus[rl], rstd = rss[rl];
#pragma unroll
      for (int ni = 0; ni < 4; ni++){
        int col = w*64 + ni*16 + lr;
        T[col*33 + rl] = (yv[mi][ni][r] - mu) * rstd * gv[ni] + bv[ni];
      }
    }
  __syncthreads();
  // write out[B,D,T]: 128 B contiguous per d
  int j = tid & 31, dq = tid >> 5;
#pragma unroll
  for (int kk2 = 0; kk2 < 32; kk2++){
    int d = dq + kk2 * 16;
    out[((size_t)(b * 512 + d)) * 1024 + t0 + j] = T[d*33 + j];
  }
}

extern "C" void kernel_launch(void* const* d_in, const int* in_sizes, int n_in,
                              void* d_out, int out_size, void* d_ws, size_t ws_size,
                              hipStream_t stream) {
  (void)in_sizes; (void)n_in; (void)out_size; (void)ws_size;
  const float* x     = (const float*)d_in[0];
  const float* W     = (const float*)d_in[1];
  const float* a_src = (const float*)d_in[2];
  const float* a_dst = (const float*)d_in[3];
  const float* W2    = (const float*)d_in[4];
  const float* b2    = (const float*)d_in[5];
  const float* ln_g  = (const float*)d_in[6];
  const float* ln_b  = (const float*)d_in[7];
  char* ws = (char*)d_ws;
  int*   sel   = (int*)  (ws + 256);
  float* mags  = (float*)(ws + 33024);
  float* es    = (float*)(ws + 1124608);
  float* ed    = (float*)(ws + 1386752);
  float* cn    = (float*)(ws + 1648896);   // 16 KB (zeroed in k_gemm_wh h==0 blocks)
  u16*   WhT   = (u16*)  (ws + 2097152);   // 8 MB; dead after k_attn
  u16*   t2b   = (u16*)  (ws + 18874368);  // 8 MB
  u16*   W2T   = (u16*)  (ws + 36175872);  // 512 KB bf16 W2[n][k] (written by k_gemm_wh h==2)
  float* out   = (float*)d_out;

  k_gemm_wh  <<<dim3(64, 8), 256, 0, stream>>>(x, W, W2, a_src, a_dst, WhT, es, ed, mags, cn, W2T);
  k_select   <<<dim3(NB, 16), 256, 0, stream>>>(mags, sel);
  k_attn     <<<dim3(64, 16), 256, 0, stream>>>(WhT, es, ed, sel, t2b, cn);
  k_gemm2ln  <<<dim3(256), 512, 0, stream>>>(t2b, W2T, x, b2, cn, ln_g, ln_b, out);
}